// Round 8
// baseline (676.550 us; speedup 1.0000x reference)
//
#include <hip/hip_runtime.h>
#include <hip/hip_bf16.h>

#define D 96
#define ASTR 104       // aT stride (halves): 208B rows, 16B-aligned, 2-way banks (free)
#define WSTR 104       // weight stride (halves)

typedef __attribute__((ext_vector_type(8))) short short8;   // 8 bf16 = 4 VGPRs
typedef __attribute__((ext_vector_type(4))) float f32x4v;   // MFMA accumulator

struct u3 { unsigned x, y, z; };                            // 12B row chunk (dwordx3)

__device__ inline float blo(unsigned u) { return __uint_as_float(u << 16); }
__device__ inline float bhi(unsigned u) { return __uint_as_float(u & 0xffff0000u); }

// ---------------- front kernel: copyx + weight prep + count(+rank) ----------------
// three disjoint work ranges run concurrently: BW-bound copy overlaps atomic-bound count.
// rowcnt/donecnt/barriers pre-zeroed by a single hipMemsetAsync.
__global__ __launch_bounds__(256) void k_front(const float* __restrict__ x,
                                               float* __restrict__ out,
                                               __hip_bfloat16* __restrict__ h16,
                                               const float* __restrict__ w10,
                                               const float* __restrict__ w20,
                                               const float* __restrict__ w11,
                                               const float* __restrict__ w21,
                                               const float* __restrict__ w12,
                                               const float* __restrict__ w22,
                                               __hip_bfloat16* __restrict__ wTg,
                                               const int* __restrict__ dst,
                                               int* __restrict__ rowcnt,
                                               unsigned short* __restrict__ rank,
                                               int n, int E) {
    int idx = blockIdx.x * 256 + threadIdx.x;
    int w0 = n * 24;                       // copyx work: n*24 float4s
    if (idx < w0) {
        int r = idx / 24, c = idx - r * 24;
        float4 v = ((const float4*)x)[idx];
        ((float4*)out)[r * 96 + c] = v;
        union { __hip_bfloat16 hh[4]; uint2 u; } p;
        p.hh[0] = __float2bfloat16(v.x); p.hh[1] = __float2bfloat16(v.y);
        p.hh[2] = __float2bfloat16(v.z); p.hh[3] = __float2bfloat16(v.w);
        ((uint2*)h16)[idx] = p.u;
        return;
    }
    idx -= w0;
    if (idx < 6 * 9216) {                  // weight prep: fp32 [k][n] -> bf16 T [n][k]
        int m = idx / 9216, i = idx - m * 9216;
        int k = i / 96, nn = i - k * 96;
        const float* W;
        switch (m) {
            case 0: W = w10; break; case 1: W = w20; break;
            case 2: W = w11; break; case 3: W = w21; break;
            case 4: W = w12; break; default: W = w22; break;
        }
        wTg[(size_t)m * (96 * WSTR) + nn * WSTR + k] = __float2bfloat16(W[k * 96 + nn]);
        return;
    }
    idx -= 6 * 9216;
    if (idx < E)                           // degree count; atomic return value = rank
        rank[idx] = (unsigned short)atomicAdd(&rowcnt[dst[idx]], 1);
}

// ---------------- scan: per-block exclusive partials + last-block scans block sums ----------------
__global__ __launch_bounds__(256) void k_scan(const int* __restrict__ cnt,
                                              int* __restrict__ raw,
                                              int* __restrict__ bsum,
                                              int* __restrict__ boff,
                                              unsigned* __restrict__ donecnt,
                                              int nb, int n) {
    __shared__ int s[256];
    __shared__ int lastflag;
    int t = threadIdx.x, b = blockIdx.x;
    int i = b * 256 + t;
    int v = (i < n) ? cnt[i] : 0;
    s[t] = v;
    __syncthreads();
    for (int off = 1; off < 256; off <<= 1) {
        int u = (t >= off) ? s[t - off] : 0;
        __syncthreads();
        s[t] += u;
        __syncthreads();
    }
    if (i < n) raw[i] = s[t] - v;          // exclusive within block
    if (t == 255) {
        atomicExch(&bsum[b], s[255]);      // device-scope publish of block total
        __threadfence();
        unsigned d = atomicAdd(donecnt, 1);
        lastflag = (d == (unsigned)(nb - 1));
    }
    __syncthreads();
    if (lastflag) {                        // last-arriving block scans the block sums
        int vv = (t < nb) ? atomicAdd(&bsum[t], 0) : 0;   // device-scope read
        s[t] = vv;
        __syncthreads();
        for (int off = 1; off < 256; off <<= 1) {
            int u = (t >= off) ? s[t - off] : 0;
            __syncthreads();
            s[t] += u;
            __syncthreads();
        }
        if (t < nb) boff[t] = s[t] - vv;   // exclusive block offsets
    }
}

// ---------------- atomic-free XCD-partitioned scatter ----------------
__global__ __launch_bounds__(256) void k_scatter(const int* __restrict__ src,
                                                 const int* __restrict__ dst,
                                                 const unsigned short* __restrict__ rank,
                                                 const int* __restrict__ raw,
                                                 const int* __restrict__ boff,
                                                 unsigned short* __restrict__ ecsr,
                                                 int E, int psz) {
    int part = blockIdx.x & 7;
    int lo = part * psz;
    int hi = lo + psz;
    int bi = blockIdx.x >> 3;
    int nb = gridDim.x >> 3;
    int stride = nb * 256;
    for (int e = bi * 256 + threadIdx.x; e < E; e += stride) {
        int d = dst[e];
        if (d >= lo && d < hi)
            ecsr[raw[d] + boff[d >> 8] + (int)rank[e]] = (unsigned short)src[e];
    }
}

// ---------------- all 3 GIN layers in ONE dispatch ----------------
// 64 rows/block, 256 threads, grid=782 (co-resident: LDS 33,280B -> 4 blk/CU = 1024 cap;
// launch_bounds(256,4) -> <=128 VGPR -> 16 waves/CU). Grid barrier between layers uses
// device-scope atomics (k_scan-proven pattern) + __threadfence release/acquire for the
// bulk h ping-pong across XCD L2s.
__global__ __launch_bounds__(256, 4) void k_layers(__hip_bfloat16* __restrict__ h_a,
                                                   __hip_bfloat16* __restrict__ h_b,
                                                   const int* __restrict__ raw,
                                                   const int* __restrict__ boff,
                                                   const unsigned short* __restrict__ ecsr,
                                                   const __hip_bfloat16* __restrict__ wTg,
                                                   const float* __restrict__ B10,
                                                   const float* __restrict__ B20,
                                                   const float* __restrict__ B11,
                                                   const float* __restrict__ B21,
                                                   const float* __restrict__ B12,
                                                   const float* __restrict__ B22,
                                                   float* __restrict__ out,
                                                   int* __restrict__ bar,
                                                   int n, int E) {
    __shared__ __align__(16) short aT[64 * ASTR];   // aggregated rows / y1, bf16
    __shared__ __align__(16) short wS[96 * WSTR];   // current weight, bf16 transposed

    const int tid = threadIdx.x;
    const int row0 = blockIdx.x * 64;
    const int lane = tid & 63;
    const int wv = __builtin_amdgcn_readfirstlane(tid >> 6);
    const int wr0 = wv * 16;                         // wave's row band
    const int quad = lane >> 4;
    const int r = lane & 15;
    const int nblk = gridDim.x;

    for (int l = 0; l < 3; l++) {
        const __hip_bfloat16* hin  = (l & 1) ? h_b : h_a;
        __hip_bfloat16*       hout = (l & 1) ? h_a : h_b;
        const __hip_bfloat16* w1t = wTg + (size_t)(2 * l) * (96 * WSTR);
        const __hip_bfloat16* w2t = wTg + (size_t)(2 * l + 1) * (96 * WSTR);
        const float* B1 = (l == 0) ? B10 : (l == 1) ? B11 : B12;
        const float* B2 = (l == 0) ? B20 : (l == 1) ? B21 : B22;
        const int ocol = (l + 1) * D;

        // stage W1 (issues first; lands under the gather latency)
        {
            const unsigned* wsrc = (const unsigned*)w1t;
            unsigned* wdst = (unsigned*)wS;
            for (int idx = tid; idx < 96 * WSTR / 2; idx += 256) wdst[idx] = wsrc[idx];
        }

        // ---- aggregation: t[i] = h[i] + sum_j h[src_j], straight into aT ----
        {
            const int ng = tid >> 4;                // node-group 0..15
            const int gl = tid & 15;                // lane within group
            const u3* hp = (const u3*)hin;          // 16 u3 per 192B row
            #pragma unroll
            for (int it = 0; it < 4; it++) {
                int rr = ng + it * 16;              // local row 0..63
                int gr = row0 + rr; if (gr >= n) gr = n - 1;
                u3 u = hp[(size_t)gr * 16 + gl];    // self term (eps=0)
                float a0 = blo(u.x), a1 = bhi(u.x), a2 = blo(u.y),
                      a3 = bhi(u.y), a4 = blo(u.z), a5 = bhi(u.z);
                int e0 = raw[gr] + boff[gr >> 8];
                int e1 = (gr + 1 == n) ? E : raw[gr + 1] + boff[(gr + 1) >> 8];
                int k = e0;
                for (; k + 8 <= e1; k += 8) {       // 8 gathers in flight
                    int s_[8];
                    #pragma unroll
                    for (int j = 0; j < 8; j++) s_[j] = ecsr[k + j];
                    u3 v_[8];
                    #pragma unroll
                    for (int j = 0; j < 8; j++) v_[j] = hp[(size_t)s_[j] * 16 + gl];
                    #pragma unroll
                    for (int j = 0; j < 8; j++) {
                        a0 += blo(v_[j].x); a1 += bhi(v_[j].x);
                        a2 += blo(v_[j].y); a3 += bhi(v_[j].y);
                        a4 += blo(v_[j].z); a5 += bhi(v_[j].z);
                    }
                }
                for (; k + 4 <= e1; k += 4) {
                    int s0 = ecsr[k], s1 = ecsr[k + 1], s2 = ecsr[k + 2], s3 = ecsr[k + 3];
                    u3 v0 = hp[(size_t)s0 * 16 + gl];
                    u3 v1 = hp[(size_t)s1 * 16 + gl];
                    u3 v2 = hp[(size_t)s2 * 16 + gl];
                    u3 v3 = hp[(size_t)s3 * 16 + gl];
                    a0 += blo(v0.x) + blo(v1.x) + blo(v2.x) + blo(v3.x);
                    a1 += bhi(v0.x) + bhi(v1.x) + bhi(v2.x) + bhi(v3.x);
                    a2 += blo(v0.y) + blo(v1.y) + blo(v2.y) + blo(v3.y);
                    a3 += bhi(v0.y) + bhi(v1.y) + bhi(v2.y) + bhi(v3.y);
                    a4 += blo(v0.z) + blo(v1.z) + blo(v2.z) + blo(v3.z);
                    a5 += bhi(v0.z) + bhi(v1.z) + bhi(v2.z) + bhi(v3.z);
                }
                for (; k < e1; k++) {
                    int s = ecsr[k];
                    u3 v = hp[(size_t)s * 16 + gl];
                    a0 += blo(v.x); a1 += bhi(v.x); a2 += blo(v.y);
                    a3 += bhi(v.y); a4 += blo(v.z); a5 += bhi(v.z);
                }
                union { __hip_bfloat16 hh[6]; u3 uu; } p;
                p.hh[0] = __float2bfloat16(a0); p.hh[1] = __float2bfloat16(a1);
                p.hh[2] = __float2bfloat16(a2); p.hh[3] = __float2bfloat16(a3);
                p.hh[4] = __float2bfloat16(a4); p.hh[5] = __float2bfloat16(a5);
                *(u3*)&aT[rr * ASTR + gl * 6] = p.uu;
            }
        }
        __syncthreads();

        // A fragments: A[m=r][k=quad*8+j]
        short8 af[3];
        #pragma unroll
        for (int ksi = 0; ksi < 3; ksi++)
            af[ksi] = *(const short8*)&aT[(wr0 + r) * ASTR + ksi * 32 + quad * 8];

        // ---- pass 1 ----
        f32x4v c1[6];
        #pragma unroll
        for (int nt = 0; nt < 6; nt++) {
            f32x4v c = {0.f, 0.f, 0.f, 0.f};
            #pragma unroll
            for (int ksi = 0; ksi < 3; ksi++) {
                short8 bfr = *(const short8*)&wS[(nt * 16 + r) * WSTR + ksi * 32 + quad * 8];
                c = __builtin_amdgcn_mfma_f32_16x16x32_bf16(af[ksi], bfr, c, 0, 0, 0);
            }
            c1[nt] = c;
        }
        __syncthreads();                             // everyone done reading W1

        // y1 = relu(c + b1) -> bf16 into own band of aT; restage W2
        #pragma unroll
        for (int nt = 0; nt < 6; nt++) {
            float bv = B1[nt * 16 + r];
            #pragma unroll
            for (int i = 0; i < 4; i++) {
                float y = fmaxf(c1[nt][i] + bv, 0.f);
                __hip_bfloat16 hb = __float2bfloat16(y);
                aT[(wr0 + quad * 4 + i) * ASTR + nt * 16 + r] = *(short*)&hb;
            }
        }
        {
            const unsigned* wsrc = (const unsigned*)w2t;
            unsigned* wdst = (unsigned*)wS;
            for (int idx = tid; idx < 96 * WSTR / 2; idx += 256) wdst[idx] = wsrc[idx];
        }
        __syncthreads();

        // ---- pass 2 ----
        short8 af2[3];
        #pragma unroll
        for (int ksi = 0; ksi < 3; ksi++)
            af2[ksi] = *(const short8*)&aT[(wr0 + r) * ASTR + ksi * 32 + quad * 8];

        #pragma unroll
        for (int nt = 0; nt < 6; nt++) {
            f32x4v c = {0.f, 0.f, 0.f, 0.f};
            #pragma unroll
            for (int ksi = 0; ksi < 3; ksi++) {
                short8 bfr = *(const short8*)&wS[(nt * 16 + r) * WSTR + ksi * 32 + quad * 8];
                c = __builtin_amdgcn_mfma_f32_16x16x32_bf16(af2[ksi], bfr, c, 0, 0, 0);
            }
            float bv = B2[nt * 16 + r];
            int col = nt * 16 + r;
            #pragma unroll
            for (int i = 0; i < 4; i++) {
                int gr = row0 + wr0 + quad * 4 + i;
                if (gr < n) {
                    float v = c[i] + bv;
                    out[(size_t)gr * 384 + ocol + col] = v;
                    if (l < 2)                      // layer 2's h-store is dead
                        hout[(size_t)gr * D + col] = __float2bfloat16(v);
                }
            }
        }

        // ---- grid barrier between layers (release -> publish -> poll -> acquire) ----
        if (l < 2) {
            __threadfence();                         // release: each thread's stores visible
            __syncthreads();
            if (tid == 0) {
                atomicAdd(&bar[l], 1);
                while (atomicAdd(&bar[l], 0) < nblk) { }
            }
            __syncthreads();
            __threadfence();                         // acquire: drop stale L1/L2 lines
        }
    }
}

extern "C" void kernel_launch(void* const* d_in, const int* in_sizes, int n_in,
                              void* d_out, int out_size, void* d_ws, size_t ws_size,
                              hipStream_t stream) {
    const float* x = (const float*)d_in[0];
    const int* ei = (const int*)d_in[1];
    const int n = in_sizes[0] / D;           // 50000
    const int E = in_sizes[1] / 2;           // 800000
    const int* src = ei;
    const int* dst = ei + E;
    float* out = (float*)d_out;

    // workspace layout (byte offsets, all 16B-aligned)
    char* ws = (char*)d_ws;
    __hip_bfloat16* h_a  = (__hip_bfloat16*)ws;                  // n*96 halves = 9.6 MB
    __hip_bfloat16* h_b  = (__hip_bfloat16*)(ws + 9600000);      // n*96 halves = 9.6 MB
    __hip_bfloat16* wTg  = (__hip_bfloat16*)(ws + 19200000);     // 6*96*104 halves ~ 120 KB
    int*      rowcnt  = (int*)(ws + 19400000);                   // n ints = 200 KB
    unsigned* donecnt = (unsigned*)(ws + 19600000);              // 4 B
    int*      bar     = (int*)(ws + 19600004);                   // 2 ints (layer barriers)
    int*      raw     = (int*)(ws + 19600016);                   // n ints (block-local excl)
    int*      bsum    = (int*)(ws + 19800032);                   // <=256 ints
    int*      boff    = (int*)(ws + 19801056);                   // <=256 ints
    unsigned short* rank = (unsigned short*)(ws + 19802080);     // E ushorts = 1.6 MB
    unsigned short* ecsr = (unsigned short*)(ws + 21402080);     // E ushorts = 1.6 MB

    // zero rowcnt + donecnt + barrier counters in one shot (200016 B)
    hipMemsetAsync(rowcnt, 0, 200016, stream);

    // front: out[:,0:96]=x, h_a=bf16(x), weights->bf16T, degree count + ranks
    const int front_work = n * 24 + 6 * 9216 + E;
    k_front<<<(front_work + 255) / 256, 256, 0, stream>>>(
        x, out, h_a,
        (const float*)d_in[2], (const float*)d_in[4],
        (const float*)d_in[6], (const float*)d_in[8],
        (const float*)d_in[10], (const float*)d_in[12],
        wTg, dst, rowcnt, rank, n, E);

    // scan (up+mid fused via done-counter), scatter (atomic-free, XCD-partitioned)
    const int NBS = (n + 255) / 256;         // 196
    k_scan<<<NBS, 256, 0, stream>>>(rowcnt, raw, bsum, boff, donecnt, NBS, n);
    const int psz = (n + 7) / 8;             // 6250
    k_scatter<<<2048, 256, 0, stream>>>(src, dst, rank, raw, boff, ecsr, E, psz);

    // all 3 layers, one dispatch (782 blocks, co-resident, 2 internal grid barriers)
    const int mlp_grid = (n + 63) / 64;      // 782
    k_layers<<<mlp_grid, 256, 0, stream>>>(
        h_a, h_b, raw, boff, ecsr, wTg,
        (const float*)d_in[3], (const float*)d_in[5],
        (const float*)d_in[7], (const float*)d_in[9],
        (const float*)d_in[11], (const float*)d_in[13],
        out, bar, n, E);
}

// Round 9
// 286.906 us; speedup vs baseline: 2.3581x; 2.3581x over previous
//
#include <hip/hip_runtime.h>
#include <hip/hip_bf16.h>

#define D 96
#define ASTR 96        // aT stride (halves): 192B rows, 16B-aligned for b128
#define WSTR 104       // weight stride (halves)

typedef __attribute__((ext_vector_type(8))) short short8;   // 8 bf16 = 4 VGPRs
typedef __attribute__((ext_vector_type(4))) float f32x4v;   // MFMA accumulator

struct u3 { unsigned x, y, z; };                            // 12B row chunk (dwordx3)

__device__ inline float blo(unsigned u) { return __uint_as_float(u << 16); }
__device__ inline float bhi(unsigned u) { return __uint_as_float(u & 0xffff0000u); }

// ---------------- front kernel: copyx + weight prep + count(+rank) ----------------
// three disjoint work ranges run concurrently: BW-bound copy overlaps atomic-bound count.
// rowcnt/donecnt pre-zeroed by a single hipMemsetAsync.
__global__ __launch_bounds__(256) void k_front(const float* __restrict__ x,
                                               float* __restrict__ out,
                                               __hip_bfloat16* __restrict__ h16,
                                               const float* __restrict__ w10,
                                               const float* __restrict__ w20,
                                               const float* __restrict__ w11,
                                               const float* __restrict__ w21,
                                               const float* __restrict__ w12,
                                               const float* __restrict__ w22,
                                               __hip_bfloat16* __restrict__ wTg,
                                               const int* __restrict__ dst,
                                               int* __restrict__ rowcnt,
                                               unsigned short* __restrict__ rank,
                                               int n, int E) {
    int idx = blockIdx.x * 256 + threadIdx.x;
    int w0 = n * 24;                       // copyx work: n*24 float4s
    if (idx < w0) {
        int r = idx / 24, c = idx - r * 24;
        float4 v = ((const float4*)x)[idx];
        ((float4*)out)[r * 96 + c] = v;
        union { __hip_bfloat16 hh[4]; uint2 u; } p;
        p.hh[0] = __float2bfloat16(v.x); p.hh[1] = __float2bfloat16(v.y);
        p.hh[2] = __float2bfloat16(v.z); p.hh[3] = __float2bfloat16(v.w);
        ((uint2*)h16)[idx] = p.u;
        return;
    }
    idx -= w0;
    if (idx < 6 * 9216) {                  // weight prep: fp32 [k][n] -> bf16 T [n][k]
        int m = idx / 9216, i = idx - m * 9216;
        int k = i / 96, nn = i - k * 96;
        const float* W;
        switch (m) {
            case 0: W = w10; break; case 1: W = w20; break;
            case 2: W = w11; break; case 3: W = w21; break;
            case 4: W = w12; break; default: W = w22; break;
        }
        wTg[(size_t)m * (96 * WSTR) + nn * WSTR + k] = __float2bfloat16(W[k * 96 + nn]);
        return;
    }
    idx -= 6 * 9216;
    if (idx < E)                           // degree count; atomic return value = rank
        rank[idx] = (unsigned short)atomicAdd(&rowcnt[dst[idx]], 1);
}

// ---------------- scan: per-block exclusive partials + last-block scans block sums ----------------
__global__ __launch_bounds__(256) void k_scan(const int* __restrict__ cnt,
                                              int* __restrict__ raw,
                                              int* __restrict__ bsum,
                                              int* __restrict__ boff,
                                              unsigned* __restrict__ donecnt,
                                              int nb, int n) {
    __shared__ int s[256];
    __shared__ int lastflag;
    int t = threadIdx.x, b = blockIdx.x;
    int i = b * 256 + t;
    int v = (i < n) ? cnt[i] : 0;
    s[t] = v;
    __syncthreads();
    for (int off = 1; off < 256; off <<= 1) {
        int u = (t >= off) ? s[t - off] : 0;
        __syncthreads();
        s[t] += u;
        __syncthreads();
    }
    if (i < n) raw[i] = s[t] - v;          // exclusive within block
    if (t == 255) {
        atomicExch(&bsum[b], s[255]);      // device-scope publish of block total
        __threadfence();
        unsigned d = atomicAdd(donecnt, 1);
        lastflag = (d == (unsigned)(nb - 1));
    }
    __syncthreads();
    if (lastflag) {                        // last-arriving block scans the block sums
        int vv = (t < nb) ? atomicAdd(&bsum[t], 0) : 0;   // device-scope read
        s[t] = vv;
        __syncthreads();
        for (int off = 1; off < 256; off <<= 1) {
            int u = (t >= off) ? s[t - off] : 0;
            __syncthreads();
            s[t] += u;
            __syncthreads();
        }
        if (t < nb) boff[t] = s[t] - vv;   // exclusive block offsets
    }
}

// ---------------- atomic-free XCD-partitioned scatter ----------------
// partition p = blockIdx&7 owns dst in [p*psz,(p+1)*psz): its ~200KB ecsr window
// write-combines in one XCD's L2. pos = raw[d] + boff[d>>8] + rank[e].
__global__ __launch_bounds__(256) void k_scatter(const int* __restrict__ src,
                                                 const int* __restrict__ dst,
                                                 const unsigned short* __restrict__ rank,
                                                 const int* __restrict__ raw,
                                                 const int* __restrict__ boff,
                                                 unsigned short* __restrict__ ecsr,
                                                 int E, int psz) {
    int part = blockIdx.x & 7;
    int lo = part * psz;
    int hi = lo + psz;
    int bi = blockIdx.x >> 3;
    int nb = gridDim.x >> 3;
    int stride = nb * 256;
    for (int e = bi * 256 + threadIdx.x; e < E; e += stride) {
        int d = dst[e];
        if (d >= lo && d < hi)
            ecsr[raw[d] + boff[d >> 8] + (int)rank[e]] = (unsigned short)src[e];
    }
}

// ---------------- fused layer: aggregate into LDS, then MFMA MLP ----------------
// 64 rows/block, 256 threads. Split launches (one per layer): on this chip ~2-3us
// launch overhead beats any resident grid-barrier scheme (round-8 post-mortem).
__global__ __launch_bounds__(256, 5) void k_fused(const __hip_bfloat16* __restrict__ hin,
                                                  const int* __restrict__ raw,
                                                  const int* __restrict__ boff,
                                                  const unsigned short* __restrict__ ecsr,
                                                  const __hip_bfloat16* __restrict__ w1t,
                                                  const float* __restrict__ B1,
                                                  const __hip_bfloat16* __restrict__ w2t,
                                                  const float* __restrict__ B2,
                                                  __hip_bfloat16* __restrict__ hout,
                                                  float* __restrict__ out,
                                                  int n, int E, int ocol, int storeh) {
    __shared__ __align__(16) short aT[64 * ASTR];   // aggregated rows / y1, bf16
    __shared__ __align__(16) short wS[96 * WSTR];   // current weight, bf16 transposed

    const int tid = threadIdx.x;
    const int row0 = blockIdx.x * 64;
    const int lane = tid & 63;
    const int wv = __builtin_amdgcn_readfirstlane(tid >> 6);
    const int wr0 = wv * 16;                         // wave's row band
    const int quad = lane >> 4;
    const int r = lane & 15;

    // stage W1 (issues first; lands under the gather latency)
    {
        const unsigned* wsrc = (const unsigned*)w1t;
        unsigned* wdst = (unsigned*)wS;
        for (int idx = tid; idx < 96 * WSTR / 2; idx += 256) wdst[idx] = wsrc[idx];
    }

    // ---- aggregation phase: t[i] = h[i] + sum_j h[src_j], straight into aT ----
    {
        const int ng = tid >> 4;                    // node-group 0..15
        const int gl = tid & 15;                    // lane within group
        const u3* hp = (const u3*)hin;              // 16 u3 per 192B row
        #pragma unroll
        for (int it = 0; it < 4; it++) {
            int rr = ng + it * 16;                  // local row 0..63
            int gr = row0 + rr; if (gr >= n) gr = n - 1;
            u3 u = hp[(size_t)gr * 16 + gl];        // self term (eps=0)
            float a0 = blo(u.x), a1 = bhi(u.x), a2 = blo(u.y),
                  a3 = bhi(u.y), a4 = blo(u.z), a5 = bhi(u.z);
            int e0 = raw[gr] + boff[gr >> 8];
            int e1 = (gr + 1 == n) ? E : raw[gr + 1] + boff[(gr + 1) >> 8];
            int k = e0;
            for (; k + 8 <= e1; k += 8) {           // 8 gathers in flight
                int s_[8];
                #pragma unroll
                for (int j = 0; j < 8; j++) s_[j] = ecsr[k + j];
                u3 v_[8];
                #pragma unroll
                for (int j = 0; j < 8; j++) v_[j] = hp[(size_t)s_[j] * 16 + gl];
                #pragma unroll
                for (int j = 0; j < 8; j++) {
                    a0 += blo(v_[j].x); a1 += bhi(v_[j].x);
                    a2 += blo(v_[j].y); a3 += bhi(v_[j].y);
                    a4 += blo(v_[j].z); a5 += bhi(v_[j].z);
                }
            }
            for (; k + 4 <= e1; k += 4) {
                int s0 = ecsr[k], s1 = ecsr[k + 1], s2 = ecsr[k + 2], s3 = ecsr[k + 3];
                u3 v0 = hp[(size_t)s0 * 16 + gl];
                u3 v1 = hp[(size_t)s1 * 16 + gl];
                u3 v2 = hp[(size_t)s2 * 16 + gl];
                u3 v3 = hp[(size_t)s3 * 16 + gl];
                a0 += blo(v0.x) + blo(v1.x) + blo(v2.x) + blo(v3.x);
                a1 += bhi(v0.x) + bhi(v1.x) + bhi(v2.x) + bhi(v3.x);
                a2 += blo(v0.y) + blo(v1.y) + blo(v2.y) + blo(v3.y);
                a3 += bhi(v0.y) + bhi(v1.y) + bhi(v2.y) + bhi(v3.y);
                a4 += blo(v0.z) + blo(v1.z) + blo(v2.z) + blo(v3.z);
                a5 += bhi(v0.z) + bhi(v1.z) + bhi(v2.z) + bhi(v3.z);
            }
            for (; k < e1; k++) {
                int s = ecsr[k];
                u3 v = hp[(size_t)s * 16 + gl];
                a0 += blo(v.x); a1 += bhi(v.x); a2 += blo(v.y);
                a3 += bhi(v.y); a4 += blo(v.z); a5 += bhi(v.z);
            }
            union { __hip_bfloat16 hh[6]; u3 uu; } p;
            p.hh[0] = __float2bfloat16(a0); p.hh[1] = __float2bfloat16(a1);
            p.hh[2] = __float2bfloat16(a2); p.hh[3] = __float2bfloat16(a3);
            p.hh[4] = __float2bfloat16(a4); p.hh[5] = __float2bfloat16(a5);
            *(u3*)&aT[rr * ASTR + gl * 6] = p.uu;
        }
    }
    __syncthreads();

    // A fragments: A[m=r][k=quad*8+j]
    short8 af[3];
    #pragma unroll
    for (int ksi = 0; ksi < 3; ksi++)
        af[ksi] = *(const short8*)&aT[(wr0 + r) * ASTR + ksi * 32 + quad * 8];

    // ---- pass 1 ----
    f32x4v c1[6];
    #pragma unroll
    for (int nt = 0; nt < 6; nt++) {
        f32x4v c = {0.f, 0.f, 0.f, 0.f};
        #pragma unroll
        for (int ksi = 0; ksi < 3; ksi++) {
            short8 bfr = *(const short8*)&wS[(nt * 16 + r) * WSTR + ksi * 32 + quad * 8];
            c = __builtin_amdgcn_mfma_f32_16x16x32_bf16(af[ksi], bfr, c, 0, 0, 0);
        }
        c1[nt] = c;
    }
    __syncthreads();                                 // everyone done reading W1

    // y1 = relu(c + b1) -> bf16 into own band of aT; restage W2
    #pragma unroll
    for (int nt = 0; nt < 6; nt++) {
        float bv = B1[nt * 16 + r];
        #pragma unroll
        for (int i = 0; i < 4; i++) {
            float y = fmaxf(c1[nt][i] + bv, 0.f);
            __hip_bfloat16 hb = __float2bfloat16(y);
            aT[(wr0 + quad * 4 + i) * ASTR + nt * 16 + r] = *(short*)&hb;
        }
    }
    {
        const unsigned* wsrc = (const unsigned*)w2t;
        unsigned* wdst = (unsigned*)wS;
        for (int idx = tid; idx < 96 * WSTR / 2; idx += 256) wdst[idx] = wsrc[idx];
    }
    __syncthreads();

    // ---- pass 2 ----
    short8 af2[3];
    #pragma unroll
    for (int ksi = 0; ksi < 3; ksi++)
        af2[ksi] = *(const short8*)&aT[(wr0 + r) * ASTR + ksi * 32 + quad * 8];

    #pragma unroll
    for (int nt = 0; nt < 6; nt++) {
        f32x4v c = {0.f, 0.f, 0.f, 0.f};
        #pragma unroll
        for (int ksi = 0; ksi < 3; ksi++) {
            short8 bfr = *(const short8*)&wS[(nt * 16 + r) * WSTR + ksi * 32 + quad * 8];
            c = __builtin_amdgcn_mfma_f32_16x16x32_bf16(af2[ksi], bfr, c, 0, 0, 0);
        }
        float bv = B2[nt * 16 + r];
        int col = nt * 16 + r;
        #pragma unroll
        for (int i = 0; i < 4; i++) {
            int gr = row0 + wr0 + quad * 4 + i;
            if (gr < n) {
                float v = c[i] + bv;
                out[(size_t)gr * 384 + ocol + col] = v;
                if (storeh)                          // last layer's h-store is dead
                    hout[(size_t)gr * D + col] = __float2bfloat16(v);
            }
        }
    }
}

extern "C" void kernel_launch(void* const* d_in, const int* in_sizes, int n_in,
                              void* d_out, int out_size, void* d_ws, size_t ws_size,
                              hipStream_t stream) {
    const float* x = (const float*)d_in[0];
    const int* ei = (const int*)d_in[1];
    const int n = in_sizes[0] / D;           // 50000
    const int E = in_sizes[1] / 2;           // 800000
    const int* src = ei;
    const int* dst = ei + E;
    float* out = (float*)d_out;

    // workspace layout (byte offsets, all 16B-aligned)
    char* ws = (char*)d_ws;
    __hip_bfloat16* h_a  = (__hip_bfloat16*)ws;                  // n*96 halves = 9.6 MB
    __hip_bfloat16* h_b  = (__hip_bfloat16*)(ws + 9600000);      // n*96 halves = 9.6 MB
    __hip_bfloat16* wTg  = (__hip_bfloat16*)(ws + 19200000);     // 6*96*104 halves ~ 120 KB
    int*      rowcnt  = (int*)(ws + 19400000);                   // n ints = 200 KB
    unsigned* donecnt = (unsigned*)(ws + 19600000);              // 4 B (zeroed with rowcnt)
    int*      raw     = (int*)(ws + 19600016);                   // n ints (block-local excl)
    int*      bsum    = (int*)(ws + 19800032);                   // <=256 ints
    int*      boff    = (int*)(ws + 19801056);                   // <=256 ints
    unsigned short* rank = (unsigned short*)(ws + 19802080);     // E ushorts = 1.6 MB
    unsigned short* ecsr = (unsigned short*)(ws + 21402080);     // E ushorts = 1.6 MB

    // zero rowcnt + donecnt in one shot
    hipMemsetAsync(rowcnt, 0, 200016, stream);

    // front: out[:,0:96]=x, h_a=bf16(x), weights->bf16T, degree count + ranks
    const int front_work = n * 24 + 6 * 9216 + E;
    k_front<<<(front_work + 255) / 256, 256, 0, stream>>>(
        x, out, h_a,
        (const float*)d_in[2], (const float*)d_in[4],
        (const float*)d_in[6], (const float*)d_in[8],
        (const float*)d_in[10], (const float*)d_in[12],
        wTg, dst, rowcnt, rank, n, E);

    // scan (up+mid fused via done-counter), scatter (atomic-free, XCD-partitioned)
    const int NBS = (n + 255) / 256;         // 196
    k_scan<<<NBS, 256, 0, stream>>>(rowcnt, raw, bsum, boff, donecnt, NBS, n);
    const int psz = (n + 7) / 8;             // 6250
    k_scatter<<<2048, 256, 0, stream>>>(src, dst, rank, raw, boff, ecsr, E, psz);

    const int mlp_grid = (n + 63) / 64;      // 782

    __hip_bfloat16* hin = h_a;
    __hip_bfloat16* hout = h_b;
    for (int l = 0; l < 3; l++) {
        const float* B1 = (const float*)d_in[3 + 4 * l];
        const float* B2 = (const float*)d_in[5 + 4 * l];
        const __hip_bfloat16* w1t = wTg + (size_t)(2 * l) * (96 * WSTR);
        const __hip_bfloat16* w2t = wTg + (size_t)(2 * l + 1) * (96 * WSTR);
        k_fused<<<mlp_grid, 256, 0, stream>>>(hin, raw, boff, ecsr,
                                              w1t, B1, w2t, B2,
                                              hout, out, n, E, (l + 1) * D, l < 2);
        __hip_bfloat16* tmp = hin; hin = hout; hout = tmp;
    }
}

// Round 11
// 280.134 us; speedup vs baseline: 2.4151x; 1.0242x over previous
//
#include <hip/hip_runtime.h>
#include <hip/hip_bf16.h>

#define D 96
#define ASTR 96        // aT stride (halves): 192B rows, 16B-aligned for b128
#define WSTR 104       // weight stride (halves)

typedef __attribute__((ext_vector_type(8))) short short8;   // 8 bf16 = 4 VGPRs
typedef __attribute__((ext_vector_type(4))) float f32x4v;   // MFMA accumulator

struct u3 { unsigned x, y, z; };                            // 12B row chunk (dwordx3)

__device__ inline float blo(unsigned u) { return __uint_as_float(u << 16); }
__device__ inline float bhi(unsigned u) { return __uint_as_float(u & 0xffff0000u); }

// ---------------- front kernel: copyx + weight prep + zero(rowcnt,donecnt) ----------------
// (R6-proven structure; count stays a separate grid-stride kernel — R9 showed fusing it
// into the front serializes the atomic tail behind the BW-bound copy, +9us)
__global__ __launch_bounds__(256) void k_front(const float* __restrict__ x,
                                               float* __restrict__ out,
                                               __hip_bfloat16* __restrict__ h16,
                                               const float* __restrict__ w10,
                                               const float* __restrict__ w20,
                                               const float* __restrict__ w11,
                                               const float* __restrict__ w21,
                                               const float* __restrict__ w12,
                                               const float* __restrict__ w22,
                                               __hip_bfloat16* __restrict__ wTg,
                                               uint4* __restrict__ zero4, int n) {
    int idx = blockIdx.x * 256 + threadIdx.x;
    int w0 = n * 24;                       // copyx work: n*24 float4s
    if (idx < w0) {
        int r = idx / 24, c = idx - r * 24;
        float4 v = ((const float4*)x)[idx];
        ((float4*)out)[r * 96 + c] = v;
        union { __hip_bfloat16 hh[4]; uint2 u; } p;
        p.hh[0] = __float2bfloat16(v.x); p.hh[1] = __float2bfloat16(v.y);
        p.hh[2] = __float2bfloat16(v.z); p.hh[3] = __float2bfloat16(v.w);
        ((uint2*)h16)[idx] = p.u;
        return;
    }
    idx -= w0;
    if (idx < 6 * 9216) {                  // weight prep: fp32 [k][n] -> bf16 T [n][k]
        int m = idx / 9216, i = idx - m * 9216;
        int k = i / 96, nn = i - k * 96;
        const float* W;
        switch (m) {
            case 0: W = w10; break; case 1: W = w20; break;
            case 2: W = w11; break; case 3: W = w21; break;
            case 4: W = w12; break; default: W = w22; break;
        }
        wTg[(size_t)m * (96 * WSTR) + nn * WSTR + k] = __float2bfloat16(W[k * 96 + nn]);
        return;
    }
    idx -= 6 * 9216;
    int zcnt = (n + 4 + 3) >> 2;           // rowcnt[n] + donecnt, in uint4s
    if (idx < zcnt) zero4[idx] = make_uint4(0, 0, 0, 0);
}

// ---------------- per-node in-degree histogram; atomic return value = edge rank ----------------
__global__ __launch_bounds__(256) void k_count(const int* __restrict__ dst,
                                               int* __restrict__ cnt,
                                               unsigned short* __restrict__ rank, int E) {
    int stride = gridDim.x * 256;
    for (int e = blockIdx.x * 256 + threadIdx.x; e < E; e += stride)
        rank[e] = (unsigned short)atomicAdd(&cnt[dst[e]], 1);
}

// ---------------- scan: per-block exclusive partials + last-block scans block sums ----------------
__global__ __launch_bounds__(256) void k_scan(const int* __restrict__ cnt,
                                              int* __restrict__ raw,
                                              int* __restrict__ bsum,
                                              int* __restrict__ boff,
                                              unsigned* __restrict__ donecnt,
                                              int nb, int n) {
    __shared__ int s[256];
    __shared__ int lastflag;
    int t = threadIdx.x, b = blockIdx.x;
    int i = b * 256 + t;
    int v = (i < n) ? cnt[i] : 0;
    s[t] = v;
    __syncthreads();
    for (int off = 1; off < 256; off <<= 1) {
        int u = (t >= off) ? s[t - off] : 0;
        __syncthreads();
        s[t] += u;
        __syncthreads();
    }
    if (i < n) raw[i] = s[t] - v;          // exclusive within block
    if (t == 255) {
        atomicExch(&bsum[b], s[255]);      // device-scope publish of block total
        __threadfence();
        unsigned d = atomicAdd(donecnt, 1);
        lastflag = (d == (unsigned)(nb - 1));
    }
    __syncthreads();
    if (lastflag) {                        // last-arriving block scans the block sums
        int vv = (t < nb) ? atomicAdd(&bsum[t], 0) : 0;   // device-scope read
        s[t] = vv;
        __syncthreads();
        for (int off = 1; off < 256; off <<= 1) {
            int u = (t >= off) ? s[t - off] : 0;
            __syncthreads();
            s[t] += u;
            __syncthreads();
        }
        if (t < nb) boff[t] = s[t] - vv;   // exclusive block offsets
    }
}

// ---------------- atomic-free XCD-partitioned scatter ----------------
// partition p = blockIdx&7 owns dst in [p*psz,(p+1)*psz): its ~200KB ecsr window
// write-combines in one XCD's L2. pos = raw[d] + boff[d>>8] + rank[e].
__global__ __launch_bounds__(256) void k_scatter(const int* __restrict__ src,
                                                 const int* __restrict__ dst,
                                                 const unsigned short* __restrict__ rank,
                                                 const int* __restrict__ raw,
                                                 const int* __restrict__ boff,
                                                 unsigned short* __restrict__ ecsr,
                                                 int E, int psz) {
    int part = blockIdx.x & 7;
    int lo = part * psz;
    int hi = lo + psz;
    int bi = blockIdx.x >> 3;
    int nb = gridDim.x >> 3;
    int stride = nb * 256;
    for (int e = bi * 256 + threadIdx.x; e < E; e += stride) {
        int d = dst[e];
        if (d >= lo && d < hi)
            ecsr[raw[d] + boff[d >> 8] + (int)rank[e]] = (unsigned short)src[e];
    }
}

// ---------------- fused layer: aggregate into LDS, then MFMA MLP ----------------
// 64 rows/block, 256 threads. Aggregation rows are assigned DYNAMICALLY from an LDS
// queue (Poisson-degree tail balancing: block barrier waits for makespan, not max of
// 16 static Poisson(64) groups). Gather stays 8-deep (best measured, R6).
__global__ __launch_bounds__(256, 5) void k_fused(const __hip_bfloat16* __restrict__ hin,
                                                  const int* __restrict__ raw,
                                                  const int* __restrict__ boff,
                                                  const unsigned short* __restrict__ ecsr,
                                                  const __hip_bfloat16* __restrict__ w1t,
                                                  const float* __restrict__ B1,
                                                  const __hip_bfloat16* __restrict__ w2t,
                                                  const float* __restrict__ B2,
                                                  __hip_bfloat16* __restrict__ hout,
                                                  float* __restrict__ out,
                                                  int n, int E, int ocol, int storeh) {
    __shared__ __align__(16) short aT[64 * ASTR];   // aggregated rows / y1, bf16
    __shared__ __align__(16) short wS[96 * WSTR];   // current weight, bf16 transposed
    __shared__ int rowctr;                          // dynamic row queue head

    const int tid = threadIdx.x;
    const int row0 = blockIdx.x * 64;
    const int lane = tid & 63;
    const int wv = __builtin_amdgcn_readfirstlane(tid >> 6);
    const int wr0 = wv * 16;                         // wave's row band
    const int quad = lane >> 4;
    const int r = lane & 15;

    // stage W1 (issues first; lands under the gather latency)
    {
        const unsigned* wsrc = (const unsigned*)w1t;
        unsigned* wdst = (unsigned*)wS;
        for (int idx = tid; idx < 96 * WSTR / 2; idx += 256) wdst[idx] = wsrc[idx];
    }
    if (tid == 0) rowctr = 0;
    __syncthreads();                                 // rowctr visible to all groups

    // ---- aggregation: t[i] = h[i] + sum_j h[src_j], straight into aT ----
    // 16-lane groups grab rows from the LDS queue until all 64 are done.
    {
        const int gl = lane & 15;                   // lane within group
        const int lead = lane & 48;                 // group leader's lane id (in wave)
        const u3* hp = (const u3*)hin;              // 16 u3 per 192B row
        for (;;) {
            int rr = 0;
            if (gl == 0) rr = atomicAdd(&rowctr, 1);
            rr = __shfl(rr, lead, 64);              // broadcast row to the group
            if (rr >= 64) break;
            int gr = row0 + rr; if (gr >= n) gr = n - 1;
            u3 u = hp[(size_t)gr * 16 + gl];        // self term (eps=0)
            float a0 = blo(u.x), a1 = bhi(u.x), a2 = blo(u.y),
                  a3 = bhi(u.y), a4 = blo(u.z), a5 = bhi(u.z);
            int e0 = raw[gr] + boff[gr >> 8];
            int e1 = (gr + 1 == n) ? E : raw[gr + 1] + boff[(gr + 1) >> 8];
            int k = e0;
            for (; k + 8 <= e1; k += 8) {           // 8 gathers in flight
                int s_[8];
                #pragma unroll
                for (int j = 0; j < 8; j++) s_[j] = ecsr[k + j];
                u3 v_[8];
                #pragma unroll
                for (int j = 0; j < 8; j++) v_[j] = hp[(size_t)s_[j] * 16 + gl];
                #pragma unroll
                for (int j = 0; j < 8; j++) {
                    a0 += blo(v_[j].x); a1 += bhi(v_[j].x);
                    a2 += blo(v_[j].y); a3 += bhi(v_[j].y);
                    a4 += blo(v_[j].z); a5 += bhi(v_[j].z);
                }
            }
            for (; k + 4 <= e1; k += 4) {
                int s0 = ecsr[k], s1 = ecsr[k + 1], s2 = ecsr[k + 2], s3 = ecsr[k + 3];
                u3 v0 = hp[(size_t)s0 * 16 + gl];
                u3 v1 = hp[(size_t)s1 * 16 + gl];
                u3 v2 = hp[(size_t)s2 * 16 + gl];
                u3 v3 = hp[(size_t)s3 * 16 + gl];
                a0 += blo(v0.x) + blo(v1.x) + blo(v2.x) + blo(v3.x);
                a1 += bhi(v0.x) + bhi(v1.x) + bhi(v2.x) + bhi(v3.x);
                a2 += blo(v0.y) + blo(v1.y) + blo(v2.y) + blo(v3.y);
                a3 += bhi(v0.y) + bhi(v1.y) + bhi(v2.y) + bhi(v3.y);
                a4 += blo(v0.z) + blo(v1.z) + blo(v2.z) + blo(v3.z);
                a5 += bhi(v0.z) + bhi(v1.z) + bhi(v2.z) + bhi(v3.z);
            }
            for (; k < e1; k++) {
                int s = ecsr[k];
                u3 v = hp[(size_t)s * 16 + gl];
                a0 += blo(v.x); a1 += bhi(v.x); a2 += blo(v.y);
                a3 += bhi(v.y); a4 += blo(v.z); a5 += bhi(v.z);
            }
            union { __hip_bfloat16 hh[6]; u3 uu; } p;
            p.hh[0] = __float2bfloat16(a0); p.hh[1] = __float2bfloat16(a1);
            p.hh[2] = __float2bfloat16(a2); p.hh[3] = __float2bfloat16(a3);
            p.hh[4] = __float2bfloat16(a4); p.hh[5] = __float2bfloat16(a5);
            *(u3*)&aT[rr * ASTR + gl * 6] = p.uu;
        }
    }
    __syncthreads();

    // A fragments: A[m=r][k=quad*8+j]
    short8 af[3];
    #pragma unroll
    for (int ksi = 0; ksi < 3; ksi++)
        af[ksi] = *(const short8*)&aT[(wr0 + r) * ASTR + ksi * 32 + quad * 8];

    // ---- pass 1 ----
    f32x4v c1[6];
    #pragma unroll
    for (int nt = 0; nt < 6; nt++) {
        f32x4v c = {0.f, 0.f, 0.f, 0.f};
        #pragma unroll
        for (int ksi = 0; ksi < 3; ksi++) {
            short8 bfr = *(const short8*)&wS[(nt * 16 + r) * WSTR + ksi * 32 + quad * 8];
            c = __builtin_amdgcn_mfma_f32_16x16x32_bf16(af[ksi], bfr, c, 0, 0, 0);
        }
        c1[nt] = c;
    }
    __syncthreads();                                 // everyone done reading W1

    // y1 = relu(c + b1) -> bf16 into own band of aT; restage W2
    #pragma unroll
    for (int nt = 0; nt < 6; nt++) {
        float bv = B1[nt * 16 + r];
        #pragma unroll
        for (int i = 0; i < 4; i++) {
            float y = fmaxf(c1[nt][i] + bv, 0.f);
            __hip_bfloat16 hb = __float2bfloat16(y);
            aT[(wr0 + quad * 4 + i) * ASTR + nt * 16 + r] = *(short*)&hb;
        }
    }
    {
        const unsigned* wsrc = (const unsigned*)w2t;
        unsigned* wdst = (unsigned*)wS;
        for (int idx = tid; idx < 96 * WSTR / 2; idx += 256) wdst[idx] = wsrc[idx];
    }
    __syncthreads();

    // ---- pass 2 ----
    short8 af2[3];
    #pragma unroll
    for (int ksi = 0; ksi < 3; ksi++)
        af2[ksi] = *(const short8*)&aT[(wr0 + r) * ASTR + ksi * 32 + quad * 8];

    #pragma unroll
    for (int nt = 0; nt < 6; nt++) {
        f32x4v c = {0.f, 0.f, 0.f, 0.f};
        #pragma unroll
        for (int ksi = 0; ksi < 3; ksi++) {
            short8 bfr = *(const short8*)&wS[(nt * 16 + r) * WSTR + ksi * 32 + quad * 8];
            c = __builtin_amdgcn_mfma_f32_16x16x32_bf16(af2[ksi], bfr, c, 0, 0, 0);
        }
        float bv = B2[nt * 16 + r];
        int col = nt * 16 + r;
        #pragma unroll
        for (int i = 0; i < 4; i++) {
            int gr = row0 + wr0 + quad * 4 + i;
            if (gr < n) {
                float v = c[i] + bv;
                out[(size_t)gr * 384 + ocol + col] = v;
                if (storeh)                          // last layer's h-store is dead
                    hout[(size_t)gr * D + col] = __float2bfloat16(v);
            }
        }
    }
}

extern "C" void kernel_launch(void* const* d_in, const int* in_sizes, int n_in,
                              void* d_out, int out_size, void* d_ws, size_t ws_size,
                              hipStream_t stream) {
    const float* x = (const float*)d_in[0];
    const int* ei = (const int*)d_in[1];
    const int n = in_sizes[0] / D;           // 50000
    const int E = in_sizes[1] / 2;           // 800000
    const int* src = ei;
    const int* dst = ei + E;
    float* out = (float*)d_out;

    // workspace layout (byte offsets, all 16B-aligned)
    char* ws = (char*)d_ws;
    __hip_bfloat16* h_a  = (__hip_bfloat16*)ws;                  // n*96 halves = 9.6 MB
    __hip_bfloat16* h_b  = (__hip_bfloat16*)(ws + 9600000);      // n*96 halves = 9.6 MB
    __hip_bfloat16* wTg  = (__hip_bfloat16*)(ws + 19200000);     // 6*96*104 halves ~ 120 KB
    int*      rowcnt  = (int*)(ws + 19400000);                   // n ints = 200 KB
    unsigned* donecnt = (unsigned*)(ws + 19600000);              // 4 B (zeroed with rowcnt)
    int*      raw     = (int*)(ws + 19600016);                   // n ints (block-local excl)
    int*      bsum    = (int*)(ws + 19800032);                   // <=256 ints
    int*      boff    = (int*)(ws + 19801056);                   // <=256 ints
    unsigned short* rank = (unsigned short*)(ws + 19802080);     // E ushorts = 1.6 MB
    unsigned short* ecsr = (unsigned short*)(ws + 21402080);     // E ushorts = 1.6 MB

    // front: out[:,0:96]=x, h_a=bf16(x), weights->bf16T, zero rowcnt+donecnt
    const int zcnt = (n + 4 + 3) >> 2;
    const int front_work = n * 24 + 6 * 9216 + zcnt;
    k_front<<<(front_work + 255) / 256, 256, 0, stream>>>(
        x, out, h_a,
        (const float*)d_in[2], (const float*)d_in[4],
        (const float*)d_in[6], (const float*)d_in[8],
        (const float*)d_in[10], (const float*)d_in[12],
        wTg, (uint4*)rowcnt, n);

    // CSR build: count(+rank) grid-stride, scan (fused done-counter), scatter
    k_count<<<2048, 256, 0, stream>>>(dst, rowcnt, rank, E);
    const int NBS = (n + 255) / 256;         // 196
    k_scan<<<NBS, 256, 0, stream>>>(rowcnt, raw, bsum, boff, donecnt, NBS, n);
    const int psz = (n + 7) / 8;             // 6250
    k_scatter<<<2048, 256, 0, stream>>>(src, dst, rank, raw, boff, ecsr, E, psz);

    const int mlp_grid = (n + 63) / 64;      // 782

    __hip_bfloat16* hin = h_a;
    __hip_bfloat16* hout = h_b;
    for (int l = 0; l < 3; l++) {
        const float* B1 = (const float*)d_in[3 + 4 * l];
        const float* B2 = (const float*)d_in[5 + 4 * l];
        const __hip_bfloat16* w1t = wTg + (size_t)(2 * l) * (96 * WSTR);
        const __hip_bfloat16* w2t = wTg + (size_t)(2 * l + 1) * (96 * WSTR);
        k_fused<<<mlp_grid, 256, 0, stream>>>(hin, raw, boff, ecsr,
                                              w1t, B1, w2t, B2,
                                              hout, out, n, E, (l + 1) * D, l < 2);
        __hip_bfloat16* tmp = hin; hin = hout; hout = tmp;
    }
}

// Round 12
// 272.432 us; speedup vs baseline: 2.4834x; 1.0283x over previous
//
#include <hip/hip_runtime.h>
#include <hip/hip_bf16.h>

#define D 96
#define ASTR 96        // aT stride (halves): 192B rows, 16B-aligned for b128
#define WSTR 104       // weight stride (halves)

typedef __attribute__((ext_vector_type(8))) short short8;   // 8 bf16 = 4 VGPRs
typedef __attribute__((ext_vector_type(4))) float f32x4v;   // MFMA accumulator

struct u3 { unsigned x, y, z; };                            // 12B row chunk (dwordx3)

__device__ inline float blo(unsigned u) { return __uint_as_float(u << 16); }
__device__ inline float bhi(unsigned u) { return __uint_as_float(u & 0xffff0000u); }

// ---------------- front kernel: copyx + weight prep + zero(rowcnt,donecnt) ----------------
__global__ __launch_bounds__(256) void k_front(const float* __restrict__ x,
                                               float* __restrict__ out,
                                               __hip_bfloat16* __restrict__ h16,
                                               const float* __restrict__ w10,
                                               const float* __restrict__ w20,
                                               const float* __restrict__ w11,
                                               const float* __restrict__ w21,
                                               const float* __restrict__ w12,
                                               const float* __restrict__ w22,
                                               __hip_bfloat16* __restrict__ wTg,
                                               uint4* __restrict__ zero4, int n) {
    int idx = blockIdx.x * 256 + threadIdx.x;
    int w0 = n * 24;                       // copyx work: n*24 float4s
    if (idx < w0) {
        int r = idx / 24, c = idx - r * 24;
        float4 v = ((const float4*)x)[idx];
        ((float4*)out)[r * 96 + c] = v;
        union { __hip_bfloat16 hh[4]; uint2 u; } p;
        p.hh[0] = __float2bfloat16(v.x); p.hh[1] = __float2bfloat16(v.y);
        p.hh[2] = __float2bfloat16(v.z); p.hh[3] = __float2bfloat16(v.w);
        ((uint2*)h16)[idx] = p.u;
        return;
    }
    idx -= w0;
    if (idx < 6 * 9216) {                  // weight prep: fp32 [k][n] -> bf16 T [n][k]
        int m = idx / 9216, i = idx - m * 9216;
        int k = i / 96, nn = i - k * 96;
        const float* W;
        switch (m) {
            case 0: W = w10; break; case 1: W = w20; break;
            case 2: W = w11; break; case 3: W = w21; break;
            case 4: W = w12; break; default: W = w22; break;
        }
        wTg[(size_t)m * (96 * WSTR) + nn * WSTR + k] = __float2bfloat16(W[k * 96 + nn]);
        return;
    }
    idx -= 6 * 9216;
    int zcnt = (n + 4 + 3) >> 2;           // rowcnt[n] + donecnt, in uint4s
    if (idx < zcnt) zero4[idx] = make_uint4(0, 0, 0, 0);
}

// ---------------- per-node in-degree histogram; atomic return value = edge rank ----------------
__global__ __launch_bounds__(256) void k_count(const int* __restrict__ dst,
                                               int* __restrict__ cnt,
                                               unsigned short* __restrict__ rank, int E) {
    int stride = gridDim.x * 256;
    for (int e = blockIdx.x * 256 + threadIdx.x; e < E; e += stride)
        rank[e] = (unsigned short)atomicAdd(&cnt[dst[e]], 1);
}

// ---------------- scan: per-block exclusive partials + last-block scans block sums ----------------
__global__ __launch_bounds__(256) void k_scan(const int* __restrict__ cnt,
                                              int* __restrict__ raw,
                                              int* __restrict__ bsum,
                                              int* __restrict__ boff,
                                              unsigned* __restrict__ donecnt,
                                              int nb, int n) {
    __shared__ int s[256];
    __shared__ int lastflag;
    int t = threadIdx.x, b = blockIdx.x;
    int i = b * 256 + t;
    int v = (i < n) ? cnt[i] : 0;
    s[t] = v;
    __syncthreads();
    for (int off = 1; off < 256; off <<= 1) {
        int u = (t >= off) ? s[t - off] : 0;
        __syncthreads();
        s[t] += u;
        __syncthreads();
    }
    if (i < n) raw[i] = s[t] - v;          // exclusive within block
    if (t == 255) {
        atomicExch(&bsum[b], s[255]);      // device-scope publish of block total
        __threadfence();
        unsigned d = atomicAdd(donecnt, 1);
        lastflag = (d == (unsigned)(nb - 1));
    }
    __syncthreads();
    if (lastflag) {                        // last-arriving block scans the block sums
        int vv = (t < nb) ? atomicAdd(&bsum[t], 0) : 0;   // device-scope read
        s[t] = vv;
        __syncthreads();
        for (int off = 1; off < 256; off <<= 1) {
            int u = (t >= off) ? s[t - off] : 0;
            __syncthreads();
            s[t] += u;
            __syncthreads();
        }
        if (t < nb) boff[t] = s[t] - vv;   // exclusive block offsets
    }
}

// ---------------- atomic-free XCD-partitioned scatter ----------------
__global__ __launch_bounds__(256) void k_scatter(const int* __restrict__ src,
                                                 const int* __restrict__ dst,
                                                 const unsigned short* __restrict__ rank,
                                                 const int* __restrict__ raw,
                                                 const int* __restrict__ boff,
                                                 unsigned short* __restrict__ ecsr,
                                                 int E, int psz) {
    int part = blockIdx.x & 7;
    int lo = part * psz;
    int hi = lo + psz;
    int bi = blockIdx.x >> 3;
    int nb = gridDim.x >> 3;
    int stride = nb * 256;
    for (int e = bi * 256 + threadIdx.x; e < E; e += stride) {
        int d = dst[e];
        if (d >= lo && d < hi)
            ecsr[raw[d] + boff[d >> 8] + (int)rank[e]] = (unsigned short)src[e];
    }
}

// ---------------- fused layer: aggregate into LDS, then MFMA MLP ----------------
// 512 threads/block, 64 rows/block, grid 782: 8 waves/block x 3 blocks/CU = 24 waves/CU
// (2x the gather TLP of the 256-thread version — the clean TLP experiment).
// MFMA: wave = (band = wv&3 -> 16-row band, half = wv>>2 -> 3 of 6 n-tiles).
__global__ __launch_bounds__(512, 4) void k_fused(const __hip_bfloat16* __restrict__ hin,
                                                  const int* __restrict__ raw,
                                                  const int* __restrict__ boff,
                                                  const unsigned short* __restrict__ ecsr,
                                                  const __hip_bfloat16* __restrict__ w1t,
                                                  const float* __restrict__ B1,
                                                  const __hip_bfloat16* __restrict__ w2t,
                                                  const float* __restrict__ B2,
                                                  __hip_bfloat16* __restrict__ hout,
                                                  float* __restrict__ out,
                                                  int n, int E, int ocol, int storeh) {
    __shared__ __align__(16) short aT[64 * ASTR];   // aggregated rows / y1, bf16
    __shared__ __align__(16) short wS[96 * WSTR];   // current weight, bf16 transposed
    __shared__ int rowctr;                          // dynamic row queue head

    const int tid = threadIdx.x;
    const int row0 = blockIdx.x * 64;
    const int lane = tid & 63;
    const int wv = __builtin_amdgcn_readfirstlane(tid >> 6);    // 0..7
    const int band = wv & 3;
    const int half = wv >> 2;                        // 0 or 1: n-tiles [half*3, half*3+3)
    const int wr0 = band * 16;                       // wave's row band
    const int quad = lane >> 4;
    const int r = lane & 15;

    // stage W1 (issues first; lands under the gather latency)
    {
        const unsigned* wsrc = (const unsigned*)w1t;
        unsigned* wdst = (unsigned*)wS;
        for (int idx = tid; idx < 96 * WSTR / 2; idx += 512) wdst[idx] = wsrc[idx];
    }
    if (tid == 0) rowctr = 0;
    __syncthreads();                                 // rowctr visible to all groups

    // ---- aggregation: t[i] = h[i] + sum_j h[src_j], straight into aT ----
    // 32 sixteen-lane groups grab rows from the LDS queue until all 64 are done.
    {
        const int gl = lane & 15;                   // lane within group
        const int lead = lane & 48;                 // group leader's lane id (in wave)
        const u3* hp = (const u3*)hin;              // 16 u3 per 192B row
        for (;;) {
            int rr = 0;
            if (gl == 0) rr = atomicAdd(&rowctr, 1);
            rr = __shfl(rr, lead, 64);              // broadcast row to the group
            if (rr >= 64) break;
            int gr = row0 + rr; if (gr >= n) gr = n - 1;
            u3 u = hp[(size_t)gr * 16 + gl];        // self term (eps=0)
            float a0 = blo(u.x), a1 = bhi(u.x), a2 = blo(u.y),
                  a3 = bhi(u.y), a4 = blo(u.z), a5 = bhi(u.z);
            int e0 = raw[gr] + boff[gr >> 8];
            int e1 = (gr + 1 == n) ? E : raw[gr + 1] + boff[(gr + 1) >> 8];
            int k = e0;
            for (; k + 8 <= e1; k += 8) {           // 8 gathers in flight
                int s_[8];
                #pragma unroll
                for (int j = 0; j < 8; j++) s_[j] = ecsr[k + j];
                u3 v_[8];
                #pragma unroll
                for (int j = 0; j < 8; j++) v_[j] = hp[(size_t)s_[j] * 16 + gl];
                #pragma unroll
                for (int j = 0; j < 8; j++) {
                    a0 += blo(v_[j].x); a1 += bhi(v_[j].x);
                    a2 += blo(v_[j].y); a3 += bhi(v_[j].y);
                    a4 += blo(v_[j].z); a5 += bhi(v_[j].z);
                }
            }
            for (; k + 4 <= e1; k += 4) {
                int s0 = ecsr[k], s1 = ecsr[k + 1], s2 = ecsr[k + 2], s3 = ecsr[k + 3];
                u3 v0 = hp[(size_t)s0 * 16 + gl];
                u3 v1 = hp[(size_t)s1 * 16 + gl];
                u3 v2 = hp[(size_t)s2 * 16 + gl];
                u3 v3 = hp[(size_t)s3 * 16 + gl];
                a0 += blo(v0.x) + blo(v1.x) + blo(v2.x) + blo(v3.x);
                a1 += bhi(v0.x) + bhi(v1.x) + bhi(v2.x) + bhi(v3.x);
                a2 += blo(v0.y) + blo(v1.y) + blo(v2.y) + blo(v3.y);
                a3 += bhi(v0.y) + bhi(v1.y) + bhi(v2.y) + bhi(v3.y);
                a4 += blo(v0.z) + blo(v1.z) + blo(v2.z) + blo(v3.z);
                a5 += bhi(v0.z) + bhi(v1.z) + bhi(v2.z) + bhi(v3.z);
            }
            for (; k < e1; k++) {
                int s = ecsr[k];
                u3 v = hp[(size_t)s * 16 + gl];
                a0 += blo(v.x); a1 += bhi(v.x); a2 += blo(v.y);
                a3 += bhi(v.y); a4 += blo(v.z); a5 += bhi(v.z);
            }
            union { __hip_bfloat16 hh[6]; u3 uu; } p;
            p.hh[0] = __float2bfloat16(a0); p.hh[1] = __float2bfloat16(a1);
            p.hh[2] = __float2bfloat16(a2); p.hh[3] = __float2bfloat16(a3);
            p.hh[4] = __float2bfloat16(a4); p.hh[5] = __float2bfloat16(a5);
            *(u3*)&aT[rr * ASTR + gl * 6] = p.uu;
        }
    }
    __syncthreads();

    // A fragments: A[m=r][k=quad*8+j] (both halves of a band load the same rows)
    short8 af[3];
    #pragma unroll
    for (int ksi = 0; ksi < 3; ksi++)
        af[ksi] = *(const short8*)&aT[(wr0 + r) * ASTR + ksi * 32 + quad * 8];

    // ---- pass 1: this wave's 3 n-tiles ----
    f32x4v c1[3];
    #pragma unroll
    for (int nt2 = 0; nt2 < 3; nt2++) {
        int nt = half * 3 + nt2;
        f32x4v c = {0.f, 0.f, 0.f, 0.f};
        #pragma unroll
        for (int ksi = 0; ksi < 3; ksi++) {
            short8 bfr = *(const short8*)&wS[(nt * 16 + r) * WSTR + ksi * 32 + quad * 8];
            c = __builtin_amdgcn_mfma_f32_16x16x32_bf16(af[ksi], bfr, c, 0, 0, 0);
        }
        c1[nt2] = c;
    }
    __syncthreads();                                 // everyone done reading W1

    // y1 = relu(c + b1) -> bf16 into (band rows, half columns) of aT; restage W2
    #pragma unroll
    for (int nt2 = 0; nt2 < 3; nt2++) {
        int nt = half * 3 + nt2;
        float bv = B1[nt * 16 + r];
        #pragma unroll
        for (int i = 0; i < 4; i++) {
            float y = fmaxf(c1[nt2][i] + bv, 0.f);
            __hip_bfloat16 hb = __float2bfloat16(y);
            aT[(wr0 + quad * 4 + i) * ASTR + nt * 16 + r] = *(short*)&hb;
        }
    }
    {
        const unsigned* wsrc = (const unsigned*)w2t;
        unsigned* wdst = (unsigned*)wS;
        for (int idx = tid; idx < 96 * WSTR / 2; idx += 512) wdst[idx] = wsrc[idx];
    }
    __syncthreads();

    // ---- pass 2 ----
    short8 af2[3];
    #pragma unroll
    for (int ksi = 0; ksi < 3; ksi++)
        af2[ksi] = *(const short8*)&aT[(wr0 + r) * ASTR + ksi * 32 + quad * 8];

    #pragma unroll
    for (int nt2 = 0; nt2 < 3; nt2++) {
        int nt = half * 3 + nt2;
        f32x4v c = {0.f, 0.f, 0.f, 0.f};
        #pragma unroll
        for (int ksi = 0; ksi < 3; ksi++) {
            short8 bfr = *(const short8*)&wS[(nt * 16 + r) * WSTR + ksi * 32 + quad * 8];
            c = __builtin_amdgcn_mfma_f32_16x16x32_bf16(af2[ksi], bfr, c, 0, 0, 0);
        }
        float bv = B2[nt * 16 + r];
        int col = nt * 16 + r;
        #pragma unroll
        for (int i = 0; i < 4; i++) {
            int gr = row0 + wr0 + quad * 4 + i;
            if (gr < n) {
                float v = c[i] + bv;
                out[(size_t)gr * 384 + ocol + col] = v;
                if (storeh)                          // last layer's h-store is dead
                    hout[(size_t)gr * D + col] = __float2bfloat16(v);
            }
        }
    }
}

extern "C" void kernel_launch(void* const* d_in, const int* in_sizes, int n_in,
                              void* d_out, int out_size, void* d_ws, size_t ws_size,
                              hipStream_t stream) {
    const float* x = (const float*)d_in[0];
    const int* ei = (const int*)d_in[1];
    const int n = in_sizes[0] / D;           // 50000
    const int E = in_sizes[1] / 2;           // 800000
    const int* src = ei;
    const int* dst = ei + E;
    float* out = (float*)d_out;

    // workspace layout (byte offsets, all 16B-aligned)
    char* ws = (char*)d_ws;
    __hip_bfloat16* h_a  = (__hip_bfloat16*)ws;                  // n*96 halves = 9.6 MB
    __hip_bfloat16* h_b  = (__hip_bfloat16*)(ws + 9600000);      // n*96 halves = 9.6 MB
    __hip_bfloat16* wTg  = (__hip_bfloat16*)(ws + 19200000);     // 6*96*104 halves ~ 120 KB
    int*      rowcnt  = (int*)(ws + 19400000);                   // n ints = 200 KB
    unsigned* donecnt = (unsigned*)(ws + 19600000);              // 4 B (zeroed with rowcnt)
    int*      raw     = (int*)(ws + 19600016);                   // n ints (block-local excl)
    int*      bsum    = (int*)(ws + 19800032);                   // <=256 ints
    int*      boff    = (int*)(ws + 19801056);                   // <=256 ints
    unsigned short* rank = (unsigned short*)(ws + 19802080);     // E ushorts = 1.6 MB
    unsigned short* ecsr = (unsigned short*)(ws + 21402080);     // E ushorts = 1.6 MB

    // front: out[:,0:96]=x, h_a=bf16(x), weights->bf16T, zero rowcnt+donecnt
    const int zcnt = (n + 4 + 3) >> 2;
    const int front_work = n * 24 + 6 * 9216 + zcnt;
    k_front<<<(front_work + 255) / 256, 256, 0, stream>>>(
        x, out, h_a,
        (const float*)d_in[2], (const float*)d_in[4],
        (const float*)d_in[6], (const float*)d_in[8],
        (const float*)d_in[10], (const float*)d_in[12],
        wTg, (uint4*)rowcnt, n);

    // CSR build: count(+rank) grid-stride, scan (fused done-counter), scatter
    k_count<<<2048, 256, 0, stream>>>(dst, rowcnt, rank, E);
    const int NBS = (n + 255) / 256;         // 196
    k_scan<<<NBS, 256, 0, stream>>>(rowcnt, raw, bsum, boff, donecnt, NBS, n);
    const int psz = (n + 7) / 8;             // 6250
    k_scatter<<<2048, 256, 0, stream>>>(src, dst, rank, raw, boff, ecsr, E, psz);

    const int mlp_grid = (n + 63) / 64;      // 782

    __hip_bfloat16* hin = h_a;
    __hip_bfloat16* hout = h_b;
    for (int l = 0; l < 3; l++) {
        const float* B1 = (const float*)d_in[3 + 4 * l];
        const float* B2 = (const float*)d_in[5 + 4 * l];
        const __hip_bfloat16* w1t = wTg + (size_t)(2 * l) * (96 * WSTR);
        const __hip_bfloat16* w2t = wTg + (size_t)(2 * l + 1) * (96 * WSTR);
        k_fused<<<mlp_grid, 512, 0, stream>>>(hin, raw, boff, ecsr,
                                              w1t, B1, w2t, B2,
                                              hout, out, n, E, (l + 1) * D, l < 2);
        __hip_bfloat16* tmp = hin; hin = hout; hout = tmp;
    }
}